// Round 4
// baseline (90.275 us; speedup 1.0000x reference)
//
#include <hip/hip_runtime.h>

#define NBATCH 8192
#define NELEC  16
#define NMO    32
#define NCONF  64
#define NS     8          // NUP == NDOWN == 8
#define TSTR   20         // A (fp32) row stride in floats (80 B: 16B-aligned for b128)
#define TSZ    (NMO * TSTR)
#define TSTRH  24         // D (fp16) row stride in HALVES (48 B: 16B-aligned for b128)
#define TSZH   (NMO * TSTRH)
#define BPB    8          // batches per block (R16)
#define NR     (BPB / 2)  // pair-rounds per block

typedef float    v2f   __attribute__((ext_vector_type(2)));
typedef _Float16 half8 __attribute__((ext_vector_type(8)));
typedef _Float16 half4 __attribute__((ext_vector_type(4)));

__device__ __forceinline__ v2f pkfma(v2f a, v2f b, v2f c) {
#if __has_builtin(__builtin_elementwise_fma)
    return __builtin_elementwise_fma(a, b, c);
#else
    return a * b + c;
#endif
}
__device__ __forceinline__ v2f bc2(float s) { return (v2f){s, s}; }
__device__ __forceinline__ float getel2(const v2f (&R)[4], int j) {
    return (j & 1) ? R[j >> 1].y : R[j >> 1].x;
}
__device__ __forceinline__ void setel2(v2f (&R)[4], int j, float v) {
    if (j & 1) R[j >> 1].y = v; else R[j >> 1].x = v;
}

// R16: batch-pipelined blocks. Ledger: R13 (DS restructure) neutral; R14
// (cap 128) +13us pure spills -> envelope deltas pass through; R15 (cap
// ~170, 3 waves/SIMD) neutral -> occupancy was already ~3, occupancy
// theory dead. Remaining untested stall: the per-block serial chain
// [cold global staging (~900cyc, L3 washed by the 268MB poison fill) ->
// barrier -> solve], repeated 4096x with zero self-overlap. R16 gives each
// block BPB=8 batches with double-buffered LDS and T14 issue-early/
// write-late register staging: next pair's 8 global loads issue BEFORE the
// solve, land in the alternate buffer AFTER it (vmcnt drain hidden under
// ~1500cyc solve). Configs are batch-invariant -> hoisted, loaded once.
// Exchange buffers indexed by round parity -> ONE barrier per round.
// R11/R12 numerics stand: A fp32 (fp16-A amplified by kappa -> 4e8 fail);
// D fp16 fine (enters linearly). R8: gathers from LDS, not global.
__device__ __forceinline__ void solve8T(const float* __restrict__ MOT,
                                        const _Float16* __restrict__ D2T,
                                        const int (&cols)[NS], int eoff,
                                        float& det_out, float& tr_out)
{
    v2f A2[NS][4];                    // row j, pair p = cols {2p, 2p+1}
    #pragma unroll
    for (int j = 0; j < NS; ++j) {
        const float4* pa = (const float4*)(MOT + cols[j] * TSTR + eoff);
        float4 a0 = pa[0], a1 = pa[1];
        A2[j][0] = (v2f){a0.x, a0.y};
        A2[j][1] = (v2f){a0.z, a0.w};
        A2[j][2] = (v2f){a1.x, a1.y};
        A2[j][3] = (v2f){a1.z, a1.w};
    }

    // In-place LU, no pivot (packed over column pairs) — byte-identical to R7.
    float det = 1.0f;
    #pragma unroll
    for (int k = 0; k < NS; ++k) {
        float ukk = getel2(A2[k], k);
        det *= ukk;
        float pinv = __builtin_amdgcn_rcpf(ukk);
        #pragma unroll
        for (int r = k + 1; r < NS; ++r) {
            float m = getel2(A2[r], k) * pinv;
            v2f m2 = bc2(m);
            #pragma unroll
            for (int p = (k + 1) >> 1; p < 4; ++p)
                A2[r][p] = pkfma(-m2, A2[k][p], A2[r][p]);
            setel2(A2[r], k, m);
        }
        setel2(A2[k], k, pinv);
    }

    // tr = sum_k <x(k), row_k(D')>, k pairs in v2f lanes. z[] holds y then x
    // in place (back-sub step i reads z[i]=y_i once before overwriting).
    float tr0 = 0.0f, tr1 = 0.0f;
    #pragma unroll
    for (int t = 0; t < 4; ++t) {
        const int k0 = 2 * t, k1 = 2 * t + 1;

        // D' rows k0,k1: ONE b128 each (fp16), issued early to hide latency
        half8 hd0 = *(const half8*)(D2T + cols[k0] * TSTRH + eoff);
        half8 hd1 = *(const half8*)(D2T + cols[k1] * TSTRH + eoff);

        // forward: z[i] = { y_{k0}[i], y_{k1}[i] }, y = L^-1 e_k
        v2f z[NS];
        z[k0] = (v2f){1.0f, 0.0f};
        z[k1] = (v2f){-getel2(A2[k1], k0), 1.0f};
        #pragma unroll
        for (int i = k1 + 1; i < NS; ++i) {
            v2f a = (v2f){0.0f, 0.0f};
            #pragma unroll
            for (int j = k0; j < i; ++j)
                a = pkfma(bc2(getel2(A2[i], j)), z[j], a);
            z[i] = -a;
        }

        // back (in place): U x = y, x stored over z
        #pragma unroll
        for (int i = NS - 1; i >= 0; --i) {
            v2f a = (i >= k0) ? z[i] : (v2f){0.0f, 0.0f};
            #pragma unroll
            for (int c2 = i + 1; c2 < NS; ++c2)
                a = pkfma(-bc2(getel2(A2[i], c2)), z[c2], a);
            z[i] = a * bc2(getel2(A2[i], i));
        }

        // mixed-precision dot: v_fma_mix_f32 folds the f16->f32 convert
        #pragma unroll
        for (int i = 0; i < NS; ++i) {
            tr0 = fmaf(z[i].x, (float)hd0[i], tr0);
            tr1 = fmaf(z[i].y, (float)hd1[i], tr1);
        }
    }

    det_out = det;
    tr_out  = tr0 + tr1;
}

// Block = 256 threads = 4 spin-pure waves processing BPB=8 batches in NR=4
// double-buffered pair-rounds. half = batch-within-pair, lane = config.
__global__ __launch_bounds__(256, 3)
void kp_dh_kernel(const float* __restrict__ MO,
                  const float* __restrict__ d2MO,
                  const int*   __restrict__ cfg_up,
                  const int*   __restrict__ cfg_dn,
                  float*       __restrict__ out)
{
    __shared__ float    smemA[2][2][TSZ];    // [buf][batch-half][MO^T fp32]
    __shared__ _Float16 smemD[2][2][TSZH];   // [buf][batch-half][d2MO^T fp16]
    __shared__ float    xtr [2][2][NCONF];   // [round-parity][half]: dn -> up
    __shared__ float    xdet[2][2][NCONF];

    const int tid  = threadIdx.x;
    const int half = tid >> 7;               // batch within pair (0/1)
    const int u    = tid & 127;
    const int b0   = blockIdx.x * BPB;       // first batch of this block

    // staging coordinates (fixed per thread): column-quad gather
    const int c  = u & 31;                   // mo column
    const int r0 = (u >> 5) << 2;            // electron quad base {0,4,8,12}
    const size_t goff = (size_t)(b0 + half) * NELEC * NMO + r0 * NMO + c;
    const float* pa = MO   + goff;           // advances by 2*NELEC*NMO per round
    const float* pd = d2MO + goff;

    // configs are batch-invariant: load ONCE (R16 hoist)
    const int s    = (tid >> 6) & 1;         // 0 = up wave, 1 = dn wave
    const int cidx = tid & 63;               // config index = lane
    const int* cfg = s ? cfg_dn : cfg_up;
    int4 q0 = ((const int4*)cfg)[cidx * 2 + 0];
    int4 q1 = ((const int4*)cfg)[cidx * 2 + 1];
    const int cols[NS] = {q0.x, q0.y, q0.z, q0.w, q1.x, q1.y, q1.z, q1.w};

    // prologue: stage pair 0 into buf 0
    {
        float a0 = pa[0 * NMO], a1 = pa[1 * NMO], a2 = pa[2 * NMO], a3 = pa[3 * NMO];
        float d0 = pd[0 * NMO], d1 = pd[1 * NMO], d2 = pd[2 * NMO], d3 = pd[3 * NMO];
        *(float4*)(smemA[0][half] + c * TSTR + r0) = make_float4(a0, a1, a2, a3);
        *(half4*)(smemD[0][half] + c * TSTRH + r0) =
            (half4){(_Float16)d0, (_Float16)d1, (_Float16)d2, (_Float16)d3};
    }
    __syncthreads();

    #pragma unroll
    for (int r = 0; r < NR; ++r) {
        const int cur = r & 1;

        // T14 issue-early: next pair's 8 global loads go in flight NOW;
        // their vmcnt drain happens at the LDS write AFTER the solve.
        float a0, a1, a2, a3, d0, d1, d2, d3;
        if (r + 1 < NR) {
            const size_t st = (size_t)2 * NELEC * NMO * (r + 1);
            a0 = pa[st + 0 * NMO]; a1 = pa[st + 1 * NMO];
            a2 = pa[st + 2 * NMO]; a3 = pa[st + 3 * NMO];
            d0 = pd[st + 0 * NMO]; d1 = pd[st + 1 * NMO];
            d2 = pd[st + 2 * NMO]; d3 = pd[st + 3 * NMO];
        }

        float det, tr;
        solve8T(smemA[cur][half], smemD[cur][half], cols, s * NS, det, tr);

        // write-late: land the prefetched pair in the alternate buffer
        if (r + 1 < NR) {
            *(float4*)(smemA[cur ^ 1][half] + c * TSTR + r0) =
                make_float4(a0, a1, a2, a3);
            *(half4*)(smemD[cur ^ 1][half] + c * TSTRH + r0) =
                (half4){(_Float16)d0, (_Float16)d1, (_Float16)d2, (_Float16)d3};
        }

        // spin combine via round-parity exchange buffers (single barrier:
        // round r reads xtr[cur] before it can reach barrier r+1, and the
        // next write of xtr[cur] is in round r+2, after barrier r+1).
        if (s) { xtr[cur][half][cidx] = tr; xdet[cur][half][cidx] = det; }
        __syncthreads();
        if (!s) {
            const int b = b0 + 2 * r + half;
            out[(size_t)b * NCONF + cidx] =
                -0.5f * (tr + xtr[cur][half][cidx]) * det * xdet[cur][half][cidx];
        }
    }
}

extern "C" void kernel_launch(void* const* d_in, const int* in_sizes, int n_in,
                              void* d_out, int out_size, void* d_ws, size_t ws_size,
                              hipStream_t stream)
{
    const float* MO     = (const float*)d_in[0];
    const float* d2MO   = (const float*)d_in[1];
    const int*   cfg_up = (const int*)d_in[2];
    const int*   cfg_dn = (const int*)d_in[3];
    float* out = (float*)d_out;

    dim3 grid(NBATCH / BPB);   // 1024 blocks, 8 batches each, 4 pair-rounds
    dim3 block(256);
    kp_dh_kernel<<<grid, block, 0, stream>>>(MO, d2MO, cfg_up, cfg_dn, out);
}